// Round 1
// 4047.667 us; speedup vs baseline: 2.4879x; 2.4879x over previous
//
#include <hip/hip_runtime.h>
#include <cmath>

#define B_   64
#define T_   512
#define IN_  256
#define H_   512
#define OUT_ 256
#define M_   (B_*T_)   // 32768 rows for the input-projection GEMMs

typedef __bf16 bf16x4 __attribute__((ext_vector_type(4)));
typedef __bf16 bf16x8 __attribute__((ext_vector_type(8)));
typedef float  f32x4  __attribute__((ext_vector_type(4)));

// Split fp32 into bf16 hi (truncated, exact) + bf16 lo (RN of remainder).
// hi+lo carries ~17 mantissa bits -> split-bf16 MFMA is fp32-grade.
static __device__ __forceinline__ void split_f32(float x, __bf16 &hi, __bf16 &lo) {
    unsigned u  = __float_as_uint(x);
    unsigned hu = u & 0xffff0000u;
    hi = __builtin_bit_cast(__bf16, (unsigned short)(hu >> 16));
    lo = (__bf16)(x - __uint_as_float(hu));
}

// ---------------- weight prep ----------------
__global__ void split_arr(const float* __restrict__ src, __bf16* __restrict__ hi,
                          __bf16* __restrict__ lo, int n) {
    int i = blockIdx.x * 256 + threadIdx.x;
    if (i < n) { __bf16 h, l; split_f32(src[i], h, l); hi[i] = h; lo[i] = l; }
}

__global__ void bias_comb(const float* __restrict__ a, const float* __restrict__ b,
                          float* __restrict__ o, int n) {
    int i = blockIdx.x * 256 + threadIdx.x;
    if (i < n) o[i] = a[i] + b[i];
}

// ---------------- xp GEMM: C[M,512] = A[M,K](f32) @ W[512,K]^T + bias ----------------
#define GBM 128
#define GBN 64
#define GBK 32
#define LDA 40    // LDS row stride in bf16 (32 + 8 pad -> conflict-friendly)

__global__ __launch_bounds__(256) void gemm_xp(
    const float* __restrict__ A, const __bf16* __restrict__ Whi,
    const __bf16* __restrict__ Wlo, const float* __restrict__ bias,
    float* __restrict__ C, int K)
{
    __shared__ __bf16 sAhi[GBM*LDA], sAlo[GBM*LDA], sBhi[GBN*LDA], sBlo[GBN*LDA];
    const int tid = threadIdx.x;
    const int m0 = blockIdx.y * GBM, n0 = blockIdx.x * GBN;
    const int wave = tid >> 6, lane = tid & 63, lm = lane & 15, q = lane >> 4;

    f32x4 acc[2][4];
#pragma unroll
    for (int i = 0; i < 2; ++i)
#pragma unroll
        for (int j = 0; j < 4; ++j) acc[i][j] = (f32x4){0.f,0.f,0.f,0.f};

    for (int k0 = 0; k0 < K; k0 += GBK) {
        __syncthreads();
#pragma unroll
        for (int i = 0; i < 4; ++i) {
            int c = tid + i * 256;
            int row = c >> 3, pos = c & 7;
            float4 v = *(const float4*)(&A[(size_t)(m0+row)*K + k0 + pos*4]);
            __bf16 h0,l0,h1,l1,h2,l2,h3,l3;
            split_f32(v.x,h0,l0); split_f32(v.y,h1,l1);
            split_f32(v.z,h2,l2); split_f32(v.w,h3,l3);
            *(bf16x4*)(&sAhi[row*LDA + pos*4]) = (bf16x4){h0,h1,h2,h3};
            *(bf16x4*)(&sAlo[row*LDA + pos*4]) = (bf16x4){l0,l1,l2,l3};
        }
        {
            int row = tid >> 2, pos = (tid & 3) * 8;
            *(bf16x8*)(&sBhi[row*LDA + pos]) =
                *(const bf16x8*)(&Whi[(size_t)(n0+row)*K + k0 + pos]);
            *(bf16x8*)(&sBlo[row*LDA + pos]) =
                *(const bf16x8*)(&Wlo[(size_t)(n0+row)*K + k0 + pos]);
        }
        __syncthreads();

        bf16x8 ah[2], al[2], bh[4], bl[4];
#pragma unroll
        for (int mt = 0; mt < 2; ++mt) {
            int r = wave*32 + mt*16 + lm;
            ah[mt] = *(const bf16x8*)(&sAhi[r*LDA + q*8]);
            al[mt] = *(const bf16x8*)(&sAlo[r*LDA + q*8]);
        }
#pragma unroll
        for (int nt = 0; nt < 4; ++nt) {
            int r = nt*16 + lm;
            bh[nt] = *(const bf16x8*)(&sBhi[r*LDA + q*8]);
            bl[nt] = *(const bf16x8*)(&sBlo[r*LDA + q*8]);
        }
#pragma unroll
        for (int mt = 0; mt < 2; ++mt)
#pragma unroll
            for (int nt = 0; nt < 4; ++nt) {
                acc[mt][nt] = __builtin_amdgcn_mfma_f32_16x16x32_bf16(ah[mt], bh[nt], acc[mt][nt], 0,0,0);
                acc[mt][nt] = __builtin_amdgcn_mfma_f32_16x16x32_bf16(ah[mt], bl[nt], acc[mt][nt], 0,0,0);
                acc[mt][nt] = __builtin_amdgcn_mfma_f32_16x16x32_bf16(al[mt], bh[nt], acc[mt][nt], 0,0,0);
            }
    }
#pragma unroll
    for (int mt = 0; mt < 2; ++mt)
#pragma unroll
        for (int nt = 0; nt < 4; ++nt)
#pragma unroll
            for (int r = 0; r < 4; ++r) {
                int m = m0 + wave*32 + mt*16 + q*4 + r;
                int n = n0 + nt*16 + lm;
                C[(size_t)m*H_ + n] = acc[mt][nt][r] + bias[n];
            }
}

// ---------------- recurrence v2 ----------------
// 4 batch-groups (16 rows) x 8 col-blocks (64 cols) = 32 blocks.
// Batch rows are independent -> groups never talk; barrier is 8-wide per group
// (per-block monotonic flags in one 64B line/group, RELEASE store + relaxed poll).
// h exchanged as packed (hi16|lo16) u32 via agent-scope atomics: L2-bypassing,
// coherent at L3 -> NO per-step L2 writeback/invalidate fences.
// W_hh column slice lives in REGISTERS (per wave: its 16 cols, hi+lo = 128 VGPR).
// h_t group slice (16x512, 32 KB) staged once per step into LDS, split hi/lo.
#define RLDA 520   // 512 + 8 pad (bf16): row stride 1040 B spreads banks

__global__ __launch_bounds__(256, 1) void rnn_rec2(
    const float* __restrict__ xp,                        // [B,T,H] fp32
    const __bf16* __restrict__ Whi, const __bf16* __restrict__ Wlo,  // [H,H]
    unsigned* __restrict__ hpk,                          // [2][B,H] packed hi|lo, zeroed
    float* __restrict__ out_seq,                         // [B,T,H] or null
    float* __restrict__ out_last,                        // [B,H] or null
    int* __restrict__ flags)                             // [4][16] ints, zeroed
{
    __shared__ __bf16 sAhi[16*RLDA], sAlo[16*RLDA];
    const int tid  = threadIdx.x;
    const int g    = blockIdx.x >> 3;       // batch group (16 rows)
    const int c    = blockIdx.x & 7;        // column block (64 cols)
    const int m0g  = g * 16;
    const int n0   = c * 64;
    const int wave = tid >> 6, lane = tid & 63, lm = lane & 15, q = lane >> 4;
    const int ncol = n0 + wave*16 + lm;     // this lane's output column

    // --- load this lane's W_hh fragments into registers (16 k-tiles, hi+lo) ---
    bf16x8 wh[16], wl[16];
#pragma unroll
    for (int kt = 0; kt < 16; ++kt) {
        wh[kt] = *(const bf16x8*)(&Whi[(size_t)ncol*H_ + kt*32 + q*8]);
        wl[kt] = *(const bf16x8*)(&Wlo[(size_t)ncol*H_ + kt*32 + q*8]);
    }

    const int srow = tid >> 4, sseg = tid & 15;  // staging: row 0..15, lane-contig segs
    int* const myflag = &flags[g*16 + c];
    int* const gflags = &flags[g*16];

    for (int t = 0; t < T_; ++t) {
        // prefetch xp for this step (independent of peers; hides HBM latency)
        float xr[4];
#pragma unroll
        for (int r = 0; r < 4; ++r)
            xr[r] = xp[((size_t)(m0g + q*4 + r)*T_ + t)*H_ + ncol];

        // wait until all 8 blocks of this group have published h_t
        if (t && tid == 0) {
            for (;;) {
                bool ok = true;
#pragma unroll
                for (int i = 0; i < 8; ++i)
                    ok &= (__hip_atomic_load(&gflags[i], __ATOMIC_RELAXED,
                                             __HIP_MEMORY_SCOPE_AGENT) >= t);
                if (ok) break;
                __builtin_amdgcn_s_sleep(1);
            }
        }
        __syncthreads();   // poll done; also WAR-protects LDS vs prev step's reads

        // stage h_t slice (16 x 512 packed u32 = 32 KB) -> split hi/lo LDS planes
        {
            unsigned long long* src = (unsigned long long*)
                (hpk + (size_t)(t & 1)*(B_*H_) + (size_t)(m0g + srow)*H_);
            unsigned long long vv[16];
#pragma unroll
            for (int j = 0; j < 16; ++j)   // lanes contiguous per j (coalesced)
                vv[j] = __hip_atomic_load(&src[sseg + j*16], __ATOMIC_RELAXED,
                                          __HIP_MEMORY_SCOPE_AGENT);
            __bf16* dh = &sAhi[srow*RLDA];
            __bf16* dl = &sAlo[srow*RLDA];
#pragma unroll
            for (int j = 0; j < 16; ++j) {
                unsigned p0 = (unsigned)vv[j], p1 = (unsigned)(vv[j] >> 32);
                *(unsigned*)(dh + (sseg + j*16)*2) = (p0 >> 16) | (p1 & 0xffff0000u);
                *(unsigned*)(dl + (sseg + j*16)*2) = (p0 & 0xffffu) | (p1 << 16);
            }
        }
        __syncthreads();

        // h_t @ W_hh^T for this wave's 16x16 tile (split-bf16, 3 MFMA/ktile,
        // identical accumulation order to v1 -> bit-identical results)
        f32x4 acc = (f32x4){0.f,0.f,0.f,0.f};
#pragma unroll
        for (int kt = 0; kt < 16; ++kt) {
            bf16x8 ah = *(const bf16x8*)(&sAhi[lm*RLDA + kt*32 + q*8]);
            bf16x8 al = *(const bf16x8*)(&sAlo[lm*RLDA + kt*32 + q*8]);
            acc = __builtin_amdgcn_mfma_f32_16x16x32_bf16(ah, wh[kt], acc, 0,0,0);
            acc = __builtin_amdgcn_mfma_f32_16x16x32_bf16(ah, wl[kt], acc, 0,0,0);
            acc = __builtin_amdgcn_mfma_f32_16x16x32_bf16(al, wh[kt], acc, 0,0,0);
        }

        // epilogue: tanh, publish h_{t+1} packed (L2-bypassing agent atomics)
        unsigned* hdst = hpk + (size_t)((t+1) & 1)*(B_*H_);
#pragma unroll
        for (int r = 0; r < 4; ++r) {
            int m = m0g + q*4 + r;
            float hv = tanhf(xr[r] + acc[r]);
            __bf16 hh, hl; split_f32(hv, hh, hl);
            unsigned pk = ((unsigned)__builtin_bit_cast(unsigned short, hh) << 16)
                        |  (unsigned)__builtin_bit_cast(unsigned short, hl);
            __hip_atomic_store(&hdst[(size_t)m*H_ + ncol], pk,
                               __ATOMIC_RELAXED, __HIP_MEMORY_SCOPE_AGENT);
            if (out_seq)  out_seq[((size_t)m*T_ + t)*H_ + ncol] = hv;
            if (out_last && t == T_-1) out_last[(size_t)m*H_ + ncol] = hv;
        }
        __syncthreads();   // drains vmcnt: every lane's h stores done (at L3)
        if (tid == 0)
            __hip_atomic_store(myflag, t+1, __ATOMIC_RELEASE,
                               __HIP_MEMORY_SCOPE_AGENT);
    }
}

// ---------------- output projection ----------------
__global__ __launch_bounds__(256) void out_proj(
    const float* __restrict__ hlast, const float* __restrict__ Wout,
    const float* __restrict__ bout, float* __restrict__ out)
{
    __shared__ float sh[H_];
    int b = blockIdx.x;
    for (int i = threadIdx.x; i < H_; i += 256) sh[i] = hlast[(size_t)b*H_ + i];
    __syncthreads();
    int o = threadIdx.x;
    const float* wr = &Wout[(size_t)o*H_];
    float acc = 0.f;
#pragma unroll 4
    for (int k = 0; k < H_; k += 4) {
        float4 wv = *(const float4*)(&wr[k]);
        acc += wv.x*sh[k] + wv.y*sh[k+1] + wv.z*sh[k+2] + wv.w*sh[k+3];
    }
    out[(size_t)b*OUT_ + o] = bout[o] + acc;
}

extern "C" void kernel_launch(void* const* d_in, const int* in_sizes, int n_in,
                              void* d_out, int out_size, void* d_ws, size_t ws_size,
                              hipStream_t stream)
{
    const float* x    = (const float*)d_in[0];
    const float* Wih0 = (const float*)d_in[1];
    const float* Whh0 = (const float*)d_in[2];
    const float* bih0 = (const float*)d_in[3];
    const float* bhh0 = (const float*)d_in[4];
    const float* Wih1 = (const float*)d_in[5];
    const float* Whh1 = (const float*)d_in[6];
    const float* bih1 = (const float*)d_in[7];
    const float* bhh1 = (const float*)d_in[8];
    const float* Wout = (const float*)d_in[9];
    const float* bout = (const float*)d_in[10];

    char* w = (char*)d_ws;
    size_t off = 0;
    auto alloc = [&](size_t bytes) -> void* {
        void* p = w + off; off = (off + bytes + 255) & ~(size_t)255; return p;
    };
    float*  xp     = (float*) alloc((size_t)M_*H_*4);      // 64 MB, reused for both layers
    float*  out0   = (float*) alloc((size_t)M_*H_*4);      // 64 MB, layer-0 outputs
    __bf16* wih0hi = (__bf16*)alloc((size_t)H_*IN_*2);
    __bf16* wih0lo = (__bf16*)alloc((size_t)H_*IN_*2);
    __bf16* whh0hi = (__bf16*)alloc((size_t)H_*H_*2);
    __bf16* whh0lo = (__bf16*)alloc((size_t)H_*H_*2);
    __bf16* wih1hi = (__bf16*)alloc((size_t)H_*H_*2);
    __bf16* wih1lo = (__bf16*)alloc((size_t)H_*H_*2);
    __bf16* whh1hi = (__bf16*)alloc((size_t)H_*H_*2);
    __bf16* whh1lo = (__bf16*)alloc((size_t)H_*H_*2);
    float*  bias0  = (float*) alloc(H_*4);
    float*  bias1  = (float*) alloc(H_*4);
    size_t zstart = off;                                   // zero-init region start
    unsigned* hpk0 = (unsigned*)alloc((size_t)2*B_*H_*4);  // packed h dbuf, layer 0
    unsigned* hpk1 = (unsigned*)alloc((size_t)2*B_*H_*4);  // packed h dbuf, layer 1
    int*    flags  = (int*)   alloc(512);                  // 2 layers x 4 groups x 16
    size_t zlen = off - zstart;
    float*  hlast  = (float*) alloc((size_t)B_*H_*4);
    int *flag0 = flags, *flag1 = flags + 64;

    // zero h double-buffers + flags (ws is poisoned before every launch)
    hipMemsetAsync(w + zstart, 0, zlen, stream);

    // weight split + bias combine
    split_arr<<<(H_*IN_+255)/256, 256, 0, stream>>>(Wih0, wih0hi, wih0lo, H_*IN_);
    split_arr<<<(H_*H_ +255)/256, 256, 0, stream>>>(Whh0, whh0hi, whh0lo, H_*H_);
    split_arr<<<(H_*H_ +255)/256, 256, 0, stream>>>(Wih1, wih1hi, wih1lo, H_*H_);
    split_arr<<<(H_*H_ +255)/256, 256, 0, stream>>>(Whh1, whh1hi, whh1lo, H_*H_);
    bias_comb<<<2, 256, 0, stream>>>(bih0, bhh0, bias0, H_);
    bias_comb<<<2, 256, 0, stream>>>(bih1, bhh1, bias1, H_);

    dim3 ggrid(H_/GBN, M_/GBM);  // (8, 256)
    // layer 0
    gemm_xp<<<ggrid, 256, 0, stream>>>(x, wih0hi, wih0lo, bias0, xp, IN_);
    rnn_rec2<<<32, 256, 0, stream>>>(xp, whh0hi, whh0lo, hpk0, out0, nullptr, flag0);
    // layer 1
    gemm_xp<<<ggrid, 256, 0, stream>>>(out0, wih1hi, wih1lo, bias1, xp, H_);
    rnn_rec2<<<32, 256, 0, stream>>>(xp, whh1hi, whh1lo, hpk1, nullptr, hlast, flag1);
    // output projection
    out_proj<<<B_, 256, 0, stream>>>(hlast, Wout, bout, (float*)d_out);
}

// Round 2
// 2761.006 us; speedup vs baseline: 3.6473x; 1.4660x over previous
//
#include <hip/hip_runtime.h>
#include <cmath>

#define B_   64
#define T_   512
#define IN_  256
#define H_   512
#define OUT_ 256
#define M_   (B_*T_)   // 32768 rows for the input-projection GEMM

typedef __bf16 bf16x4 __attribute__((ext_vector_type(4)));
typedef __bf16 bf16x8 __attribute__((ext_vector_type(8)));
typedef float  f32x4  __attribute__((ext_vector_type(4)));

// Split fp32 into bf16 hi (truncated, exact) + bf16 lo (RN of remainder).
static __device__ __forceinline__ void split_f32(float x, __bf16 &hi, __bf16 &lo) {
    unsigned u  = __float_as_uint(x);
    unsigned hu = u & 0xffff0000u;
    hi = __builtin_bit_cast(__bf16, (unsigned short)(hu >> 16));
    lo = (__bf16)(x - __uint_as_float(hu));
}

// ---------------- weight prep ----------------
__global__ void split_arr(const float* __restrict__ src, __bf16* __restrict__ hi,
                          __bf16* __restrict__ lo, int n) {
    int i = blockIdx.x * 256 + threadIdx.x;
    if (i < n) { __bf16 h, l; split_f32(src[i], h, l); hi[i] = h; lo[i] = l; }
}

__global__ void bias_comb(const float* __restrict__ a, const float* __restrict__ b,
                          float* __restrict__ o, int n) {
    int i = blockIdx.x * 256 + threadIdx.x;
    if (i < n) o[i] = a[i] + b[i];
}

// ---------------- xp GEMM: C[M,512] = A[M,K](f32) @ W[512,K]^T + bias ----------------
#define GBM 128
#define GBN 64
#define GBK 32
#define LDA 40

__global__ __launch_bounds__(256) void gemm_xp(
    const float* __restrict__ A, const __bf16* __restrict__ Whi,
    const __bf16* __restrict__ Wlo, const float* __restrict__ bias,
    float* __restrict__ C, int K)
{
    __shared__ __bf16 sAhi[GBM*LDA], sAlo[GBM*LDA], sBhi[GBN*LDA], sBlo[GBN*LDA];
    const int tid = threadIdx.x;
    const int m0 = blockIdx.y * GBM, n0 = blockIdx.x * GBN;
    const int wave = tid >> 6, lane = tid & 63, lm = lane & 15, q = lane >> 4;

    f32x4 acc[2][4];
#pragma unroll
    for (int i = 0; i < 2; ++i)
#pragma unroll
        for (int j = 0; j < 4; ++j) acc[i][j] = (f32x4){0.f,0.f,0.f,0.f};

    for (int k0 = 0; k0 < K; k0 += GBK) {
        __syncthreads();
#pragma unroll
        for (int i = 0; i < 4; ++i) {
            int c = tid + i * 256;
            int row = c >> 3, pos = c & 7;
            float4 v = *(const float4*)(&A[(size_t)(m0+row)*K + k0 + pos*4]);
            __bf16 h0,l0,h1,l1,h2,l2,h3,l3;
            split_f32(v.x,h0,l0); split_f32(v.y,h1,l1);
            split_f32(v.z,h2,l2); split_f32(v.w,h3,l3);
            *(bf16x4*)(&sAhi[row*LDA + pos*4]) = (bf16x4){h0,h1,h2,h3};
            *(bf16x4*)(&sAlo[row*LDA + pos*4]) = (bf16x4){l0,l1,l2,l3};
        }
        {
            int row = tid >> 2, pos = (tid & 3) * 8;
            *(bf16x8*)(&sBhi[row*LDA + pos]) =
                *(const bf16x8*)(&Whi[(size_t)(n0+row)*K + k0 + pos]);
            *(bf16x8*)(&sBlo[row*LDA + pos]) =
                *(const bf16x8*)(&Wlo[(size_t)(n0+row)*K + k0 + pos]);
        }
        __syncthreads();

        bf16x8 ah[2], al[2], bh[4], bl[4];
#pragma unroll
        for (int mt = 0; mt < 2; ++mt) {
            int r = wave*32 + mt*16 + lm;
            ah[mt] = *(const bf16x8*)(&sAhi[r*LDA + q*8]);
            al[mt] = *(const bf16x8*)(&sAlo[r*LDA + q*8]);
        }
#pragma unroll
        for (int nt = 0; nt < 4; ++nt) {
            int r = nt*16 + lm;
            bh[nt] = *(const bf16x8*)(&sBhi[r*LDA + q*8]);
            bl[nt] = *(const bf16x8*)(&sBlo[r*LDA + q*8]);
        }
#pragma unroll
        for (int mt = 0; mt < 2; ++mt)
#pragma unroll
            for (int nt = 0; nt < 4; ++nt) {
                acc[mt][nt] = __builtin_amdgcn_mfma_f32_16x16x32_bf16(ah[mt], bh[nt], acc[mt][nt], 0,0,0);
                acc[mt][nt] = __builtin_amdgcn_mfma_f32_16x16x32_bf16(ah[mt], bl[nt], acc[mt][nt], 0,0,0);
                acc[mt][nt] = __builtin_amdgcn_mfma_f32_16x16x32_bf16(al[mt], bh[nt], acc[mt][nt], 0,0,0);
            }
    }
#pragma unroll
    for (int mt = 0; mt < 2; ++mt)
#pragma unroll
        for (int nt = 0; nt < 4; ++nt)
#pragma unroll
            for (int r = 0; r < 4; ++r) {
                int m = m0 + wave*32 + mt*16 + q*4 + r;
                int n = n0 + nt*16 + lm;
                C[(size_t)m*H_ + n] = acc[mt][nt][r] + bias[n];
            }
}

// ---------------- fused pipelined recurrence (both layers + layer-1 input proj) --------
// 96 blocks, 3 roles x (4 batch-groups x 8 col-blocks):
//   role0: layer-0 recurrence; publishes packed h0 into full ring hr0[T+1][B][H]
//   role1: xp1 projection: out0_t @ W_ih1^T + bias1, written over consumed xp0 slot t
//   role2: layer-1 recurrence (reads xp1 slot t + own h1 double-buffer)
// All cross-block data via agent-scope (L2-bypassing) atomics; monotone flag DAG:
//   flag0 -> flagP -> (flag1 self). No back-pressure needed (rings are full-length).
#define RLDA 520   // 512 + 8 pad (bf16)

__global__ __launch_bounds__(256, 1) void rnn_fused(
    float* __restrict__ xp,                              // [B,T,H]: xp0, overwritten slot-wise with xp1
    const __bf16* __restrict__ w0hi, const __bf16* __restrict__ w0lo,   // W_hh0 split
    const __bf16* __restrict__ wphi, const __bf16* __restrict__ wplo,   // W_ih1 split
    const __bf16* __restrict__ w1hi, const __bf16* __restrict__ w1lo,   // W_hh1 split
    const float* __restrict__ bias1,                     // bih1+bhh1
    unsigned* __restrict__ hr0,                          // [(T+1),B,H] packed hi|lo, slot0 zeroed
    unsigned* __restrict__ h1pk,                         // [2,B,H] packed, zeroed
    float* __restrict__ hlast,                           // [B,H]
    int* __restrict__ flags)                             // [3][4][16], zeroed
{
    __shared__ __bf16 sAhi[16*RLDA], sAlo[16*RLDA];
    const int tid  = threadIdx.x;
    const int role = blockIdx.x >> 5;       // 0: L0 rec, 1: proj, 2: L1 rec
    const int sub  = blockIdx.x & 31;
    const int g    = sub >> 3;              // batch group (16 rows)
    const int c    = sub & 7;               // column block (64 cols)
    const int m0g  = g * 16;
    const int n0   = c * 64;
    const int wave = tid >> 6, lane = tid & 63, lm = lane & 15, q = lane >> 4;
    const int ncol = n0 + wave*16 + lm;
    const int srow = tid >> 4, sseg = tid & 15;

    int* const flag0 = flags + (0*4 + g)*16;
    int* const flagP = flags + (1*4 + g)*16;
    int* const flag1 = flags + (2*4 + g)*16;

    // per-role W fragments (16 k-tiles, hi+lo)
    const __bf16* Wh = (role == 0) ? w0hi : (role == 1) ? wphi : w1hi;
    const __bf16* Wl = (role == 0) ? w0lo : (role == 1) ? wplo : w1lo;
    bf16x8 wh[16], wl[16];
#pragma unroll
    for (int kt = 0; kt < 16; ++kt) {
        wh[kt] = *(const bf16x8*)(&Wh[(size_t)ncol*H_ + kt*32 + q*8]);
        wl[kt] = *(const bf16x8*)(&Wl[(size_t)ncol*H_ + kt*32 + q*8]);
    }

    unsigned* const xpu = (unsigned*)xp;

    // ---- helpers ----
    auto stage_slice = [&](const unsigned* hbase) {
        const unsigned long long* src =
            (const unsigned long long*)(hbase + (size_t)(m0g + srow)*H_);
        unsigned long long vv[16];
#pragma unroll
        for (int j = 0; j < 16; ++j)
            vv[j] = __hip_atomic_load(&src[sseg + j*16], __ATOMIC_RELAXED,
                                      __HIP_MEMORY_SCOPE_AGENT);
        __bf16* dh = &sAhi[srow*RLDA];
        __bf16* dl = &sAlo[srow*RLDA];
#pragma unroll
        for (int j = 0; j < 16; ++j) {
            unsigned p0 = (unsigned)vv[j], p1 = (unsigned)(vv[j] >> 32);
            *(unsigned*)(dh + (sseg + j*16)*2) = (p0 >> 16) | (p1 & 0xffff0000u);
            *(unsigned*)(dl + (sseg + j*16)*2) = (p0 & 0xffffu) | (p1 << 16);
        }
    };
    auto mma_tile = [&]() {
        f32x4 acc = (f32x4){0.f,0.f,0.f,0.f};
#pragma unroll
        for (int kt = 0; kt < 16; ++kt) {
            bf16x8 ah = *(const bf16x8*)(&sAhi[lm*RLDA + kt*32 + q*8]);
            bf16x8 al = *(const bf16x8*)(&sAlo[lm*RLDA + kt*32 + q*8]);
            acc = __builtin_amdgcn_mfma_f32_16x16x32_bf16(ah, wh[kt], acc, 0,0,0);
            acc = __builtin_amdgcn_mfma_f32_16x16x32_bf16(ah, wl[kt], acc, 0,0,0);
            acc = __builtin_amdgcn_mfma_f32_16x16x32_bf16(al, wh[kt], acc, 0,0,0);
        }
        return acc;
    };
    auto publish = [&](unsigned* dst, int m, float hv) {
        __bf16 hh, hl; split_f32(hv, hh, hl);
        unsigned pk = ((unsigned)__builtin_bit_cast(unsigned short, hh) << 16)
                    |  (unsigned)__builtin_bit_cast(unsigned short, hl);
        __hip_atomic_store(&dst[(size_t)m*H_ + ncol], pk,
                           __ATOMIC_RELAXED, __HIP_MEMORY_SCOPE_AGENT);
    };

    if (role == 0) {
        // ---------------- layer-0 recurrence ----------------
        for (int t = 0; t < T_; ++t) {
            float xr[4];
#pragma unroll
            for (int r = 0; r < 4; ++r)
                xr[r] = xp[((size_t)(m0g + q*4 + r)*T_ + t)*H_ + ncol];
            if (t && tid == 0) {
                for (;;) {
                    bool ok = true;
#pragma unroll
                    for (int i = 0; i < 8; ++i)
                        ok &= (__hip_atomic_load(&flag0[i], __ATOMIC_RELAXED,
                                                 __HIP_MEMORY_SCOPE_AGENT) >= t);
                    if (ok) break;
                    __builtin_amdgcn_s_sleep(1);
                }
            }
            __syncthreads();
            stage_slice(hr0 + (size_t)t*(B_*H_));
            __syncthreads();
            f32x4 acc = mma_tile();
            unsigned* dst = hr0 + (size_t)(t+1)*(B_*H_);
#pragma unroll
            for (int r = 0; r < 4; ++r) {
                int m = m0g + q*4 + r;
                float hv = tanhf(xr[r] + acc[r]);
                publish(dst, m, hv);
            }
            __syncthreads();   // drain: all lanes' stores done
            if (tid == 0)
                __hip_atomic_store(&flag0[c], t+1, __ATOMIC_RELEASE,
                                   __HIP_MEMORY_SCOPE_AGENT);
        }
    } else if (role == 1) {
        // ---------------- layer-1 input projection ----------------
        const float b1 = bias1[ncol];
        for (int t = 0; t < T_; ++t) {
            if (tid == 0) {
                for (;;) {
                    bool ok = true;
#pragma unroll
                    for (int i = 0; i < 8; ++i)
                        ok &= (__hip_atomic_load(&flag0[i], __ATOMIC_RELAXED,
                                                 __HIP_MEMORY_SCOPE_AGENT) >= t+1);
                    if (ok) break;
                    __builtin_amdgcn_s_sleep(1);
                }
            }
            __syncthreads();
            stage_slice(hr0 + (size_t)(t+1)*(B_*H_));   // = out0[:, t, :]
            __syncthreads();
            f32x4 acc = mma_tile();
#pragma unroll
            for (int r = 0; r < 4; ++r) {
                int m = m0g + q*4 + r;
                float v = acc[r] + b1;                   // exact fp32 xp1 value
                __hip_atomic_store(&xpu[((size_t)m*T_ + t)*H_ + ncol],
                                   __float_as_uint(v),
                                   __ATOMIC_RELAXED, __HIP_MEMORY_SCOPE_AGENT);
            }
            __syncthreads();
            if (tid == 0)
                __hip_atomic_store(&flagP[c], t+1, __ATOMIC_RELEASE,
                                   __HIP_MEMORY_SCOPE_AGENT);
        }
    } else {
        // ---------------- layer-1 recurrence ----------------
        for (int t = 0; t < T_; ++t) {
            if (tid == 0) {
                for (;;) {
                    bool ok = true;
#pragma unroll
                    for (int i = 0; i < 8; ++i)
                        ok &= (__hip_atomic_load(&flagP[i], __ATOMIC_RELAXED,
                                                 __HIP_MEMORY_SCOPE_AGENT) >= t+1);
                    if (t)
#pragma unroll
                        for (int i = 0; i < 8; ++i)
                            ok &= (__hip_atomic_load(&flag1[i], __ATOMIC_RELAXED,
                                                     __HIP_MEMORY_SCOPE_AGENT) >= t);
                    if (ok) break;
                    __builtin_amdgcn_s_sleep(1);
                }
            }
            __syncthreads();
            // xp1 loads (agent scope: L2-bypass, must not hit stale xp0 lines);
            // issued alongside the stage loads so both overlap in one L3 RTT.
            float xr[4];
#pragma unroll
            for (int r = 0; r < 4; ++r)
                xr[r] = __uint_as_float(__hip_atomic_load(
                    &xpu[((size_t)(m0g + q*4 + r)*T_ + t)*H_ + ncol],
                    __ATOMIC_RELAXED, __HIP_MEMORY_SCOPE_AGENT));
            stage_slice(h1pk + (size_t)(t & 1)*(B_*H_));
            __syncthreads();
            f32x4 acc = mma_tile();
            unsigned* dst = h1pk + (size_t)((t+1) & 1)*(B_*H_);
#pragma unroll
            for (int r = 0; r < 4; ++r) {
                int m = m0g + q*4 + r;
                float hv = tanhf(xr[r] + acc[r]);
                publish(dst, m, hv);
                if (t == T_-1) hlast[(size_t)m*H_ + ncol] = hv;
            }
            __syncthreads();
            if (tid == 0)
                __hip_atomic_store(&flag1[c], t+1, __ATOMIC_RELEASE,
                                   __HIP_MEMORY_SCOPE_AGENT);
        }
    }
}

// ---------------- output projection ----------------
__global__ __launch_bounds__(256) void out_proj(
    const float* __restrict__ hlast, const float* __restrict__ Wout,
    const float* __restrict__ bout, float* __restrict__ out)
{
    __shared__ float sh[H_];
    int b = blockIdx.x;
    for (int i = threadIdx.x; i < H_; i += 256) sh[i] = hlast[(size_t)b*H_ + i];
    __syncthreads();
    int o = threadIdx.x;
    const float* wr = &Wout[(size_t)o*H_];
    float acc = 0.f;
#pragma unroll 4
    for (int k = 0; k < H_; k += 4) {
        float4 wv = *(const float4*)(&wr[k]);
        acc += wv.x*sh[k] + wv.y*sh[k+1] + wv.z*sh[k+2] + wv.w*sh[k+3];
    }
    out[(size_t)b*OUT_ + o] = bout[o] + acc;
}

extern "C" void kernel_launch(void* const* d_in, const int* in_sizes, int n_in,
                              void* d_out, int out_size, void* d_ws, size_t ws_size,
                              hipStream_t stream)
{
    const float* x    = (const float*)d_in[0];
    const float* Wih0 = (const float*)d_in[1];
    const float* Whh0 = (const float*)d_in[2];
    const float* bih0 = (const float*)d_in[3];
    const float* bhh0 = (const float*)d_in[4];
    const float* Wih1 = (const float*)d_in[5];
    const float* Whh1 = (const float*)d_in[6];
    const float* bih1 = (const float*)d_in[7];
    const float* bhh1 = (const float*)d_in[8];
    const float* Wout = (const float*)d_in[9];
    const float* bout = (const float*)d_in[10];

    char* w = (char*)d_ws;
    size_t off = 0;
    auto alloc = [&](size_t bytes) -> void* {
        void* p = w + off; off = (off + bytes + 255) & ~(size_t)255; return p;
    };
    float*    xp    = (float*)   alloc((size_t)M_*H_*4);            // 64 MB: xp0, then xp1 in place
    unsigned* hr0   = (unsigned*)alloc((size_t)(T_+1)*B_*H_*4);     // 67 MB packed h0 ring
    __bf16* wih0hi = (__bf16*)alloc((size_t)H_*IN_*2);
    __bf16* wih0lo = (__bf16*)alloc((size_t)H_*IN_*2);
    __bf16* whh0hi = (__bf16*)alloc((size_t)H_*H_*2);
    __bf16* whh0lo = (__bf16*)alloc((size_t)H_*H_*2);
    __bf16* wih1hi = (__bf16*)alloc((size_t)H_*H_*2);
    __bf16* wih1lo = (__bf16*)alloc((size_t)H_*H_*2);
    __bf16* whh1hi = (__bf16*)alloc((size_t)H_*H_*2);
    __bf16* whh1lo = (__bf16*)alloc((size_t)H_*H_*2);
    float*  bias0  = (float*) alloc(H_*4);
    float*  bias1  = (float*) alloc(H_*4);
    size_t zstart = off;                                            // zero region
    unsigned* h1pk = (unsigned*)alloc((size_t)2*B_*H_*4);           // layer-1 h dbuf
    int*    flags  = (int*)   alloc(768);                           // 3 roles x 4 groups x 16
    size_t zlen = off - zstart;
    float*  hlast  = (float*) alloc((size_t)B_*H_*4);

    // zero: h1 dbuf + flags, and ring slot 0 (initial h0 = 0)
    hipMemsetAsync(w + zstart, 0, zlen, stream);
    hipMemsetAsync(hr0, 0, (size_t)B_*H_*4, stream);

    // weight split + bias combine
    split_arr<<<(H_*IN_+255)/256, 256, 0, stream>>>(Wih0, wih0hi, wih0lo, H_*IN_);
    split_arr<<<(H_*H_ +255)/256, 256, 0, stream>>>(Whh0, whh0hi, whh0lo, H_*H_);
    split_arr<<<(H_*H_ +255)/256, 256, 0, stream>>>(Wih1, wih1hi, wih1lo, H_*H_);
    split_arr<<<(H_*H_ +255)/256, 256, 0, stream>>>(Whh1, whh1hi, whh1lo, H_*H_);
    bias_comb<<<2, 256, 0, stream>>>(bih0, bhh0, bias0, H_);
    bias_comb<<<2, 256, 0, stream>>>(bih1, bhh1, bias1, H_);

    // layer-0 input projection (one big GEMM, K=256)
    dim3 ggrid(H_/GBN, M_/GBM);  // (8, 256)
    gemm_xp<<<ggrid, 256, 0, stream>>>(x, wih0hi, wih0lo, bias0, xp, IN_);

    // fused pipelined recurrences (layer0 -> proj -> layer1)
    rnn_fused<<<96, 256, 0, stream>>>(xp, whh0hi, whh0lo, wih1hi, wih1lo,
                                      whh1hi, whh1lo, bias1, hr0, h1pk, hlast, flags);

    // output projection
    out_proj<<<B_, 256, 0, stream>>>(hlast, Wout, bout, (float*)d_out);
}